// Round 13
// baseline (73.743 us; speedup 1.0000x reference)
//
#include <hip/hip_runtime.h>

// PointNet++ grouping: ball query (radius 0.2, nsample 64) + gather + concat.
// Shapes fixed by setup_inputs(): B=4, N=16384, npoint=2048, C=64.
// out[b][j][c][s]: c in [0,3) = xyz[idx]-new_xyz, c in [3,67) = features[c-3][idx].
//
// Structure (round 13 = round 12 + LPT scheduling + prefetch-2 query):
//   Kernel 1 (prep, 1028 blocks): blocks [0,1024) transpose features
//     (B,C,N)->ft(B,N,C) XCD-pinned; blocks [1024,1028) compute a per-batch
//     clip-priority REMAP (16-bucket counting sort, one block per batch):
//     centers whose ball is clipped by more cube faces have lower in-ball
//     density -> longer scans -> scheduled FIRST (LPT; kills the straggler
//     tail). Remap order only affects timing, never output values.
//   Kernel 2 (qg): fused query + cooperative gather (R12 form, 4 waves/blk,
//     regular dwordx4 stores). Query now uses prefetch DEPTH 2 (two named
//     register sets) to halve per-chunk latency exposure on long scans.

#define BB 4
#define NN 16384
#define NP 2048
#define CC 64
#define NS 64
#define CH (3 + CC)
#define NCHUNK (NN / 256)   // 64 chunks of 256 points
#define ST 65               // LDS tile row stride (floats)

typedef float f32x4 __attribute__((ext_vector_type(4)));

// ---------- Kernel 1: transpose (XCD-pinned) + clip-priority remap ----------
__global__ __launch_bounds__(256) void pn2_prep_kernel(
    const float* __restrict__ f,         // features (B, C, N)
    const float* __restrict__ new_xyz,   // (B, NP, 3)
    float* __restrict__ ft,              // ws: (B, N, C)
    int* __restrict__ remap)             // ws: (B, NP) slot -> j
{
    __shared__ float tile[CC][65];       // transpose role (16.6 KB)
    __shared__ int hist[16];             // remap role
    __shared__ int basep[16];

    const int g = blockIdx.x;

    if (g >= BB * 256) {
        // ---- remap role: one block per batch, counting sort by clip key ----
        const int b = g - BB * 256;
        const int tid = threadIdx.x;
        if (tid < 16) hist[tid] = 0;
        __syncthreads();
        int lvl[8];
#pragma unroll
        for (int it = 0; it < 8; ++it) {
            const int j = it * 256 + tid;
            const float* q = new_xyz + ((size_t)b * NP + j) * 3;
            float key = 0.f;
#pragma unroll
            for (int d = 0; d < 3; ++d) {
                const float c = q[d];
                key += fmaxf(0.f, 0.2f - fminf(c, 1.0f - c));
            }
            int l = (int)(key * 26.6666f);          // 0..16 -> clamp 15
            l = l > 15 ? 15 : l;
            lvl[it] = l;
            atomicAdd(&hist[l], 1);
        }
        __syncthreads();
        if (tid == 0) {                 // descending level -> ascending slots
            int acc = 0;
            for (int l = 15; l >= 0; --l) { basep[l] = acc; acc += hist[l]; }
        }
        __syncthreads();
#pragma unroll
        for (int it = 0; it < 8; ++it) {
            const int j = it * 256 + tid;
            const int slot = atomicAdd(&basep[lvl[it]], 1);
            remap[(size_t)b * NP + slot] = j;
        }
        return;
    }

    // ---- transpose role ----
    const int xcd = g & 7;
    const int b = xcd >> 1;                  // batch pinned to XCD pair
    const int tidx = ((xcd & 1) << 7) + (g >> 3);   // 0..255
    const int n0 = tidx << 6;
    const int col = threadIdx.x & 63;
    const int r4  = threadIdx.x >> 6;        // 0..3
    const float* src = f + (size_t)b * CC * NN;
#pragma unroll
    for (int i = 0; i < 16; ++i) {
        const int c = r4 + i * 4;
        tile[c][col] = __builtin_nontemporal_load(&src[(size_t)c * NN + n0 + col]);
    }
    __syncthreads();
    float* dst = ft + ((size_t)b * NN + n0) * CC;
#pragma unroll
    for (int i = 0; i < 16; ++i) {
        const int n = r4 + i * 4;
        dst[(size_t)n * CC + col] = tile[col][n];        // coalesced along c
    }
}

// ---------- Kernel 2: fused ball query + cooperative gather ----------
__global__ __launch_bounds__(256, 4) void pn2_qg_kernel(
    const float* __restrict__ xyz,       // (B, N, 3)
    const float* __restrict__ new_xyz,   // (B, NP, 3)
    const float* __restrict__ ft,        // ws: (B, N, C)
    const int* __restrict__ remap,       // ws: (B, NP)
    float* __restrict__ out)             // (B, NP, CH, NS)
{
    __shared__ int sidx[4][NS];
    __shared__ __align__(16) float stile[4][32 * ST];   // 33.3KB: half/wave

    const int lane = threadIdx.x & 63;
    const int wave = threadIdx.x >> 6;

    // XCD batch pinning (matches transpose): bijective over 2048 blocks.
    const int g = blockIdx.x;
    const int xcd = g & 7;
    const int cg = ((xcd >> 1) << 9) + ((xcd & 1) << 8) + (g >> 3);
    const int slot = cg * 4 + wave;             // 0 .. B*NP-1, batch-grouped
    const int b = slot >> 11;
    const int j = remap[(size_t)b * NP + (slot & (NP - 1))];  // LPT order
    const int center = b * NP + j;

    const float r2 = 0.04f;                     // f32(0.2*0.2)
    const float* q = new_xyz + ((size_t)b * NP + j) * 3;
    const float cx = q[0], cy = q[1], cz = q[2];

    const float* xb = xyz + (size_t)b * NN * 3;
    const float4* x4 = (const float4*)xb;
    int* widx = sidx[wave];

    // ---- query: 4 pts/lane (48B = 3x float4), prefetch DEPTH 2 ----
    const int base = 3 * lane;
    const unsigned long long low = (1ull << lane) - 1ull;
    int found = 0;
    int it = 0;

    float4 A0 = x4[base],       B0 = x4[base + 1],       C0 = x4[base + 2];
    float4 A1 = x4[192 + base], B1 = x4[192 + base + 1], C1 = x4[192 + base + 2];

#define QPROC(Ar, Br, Cr)                                                      \
    {                                                                          \
        const int n0 = it * 256 + 4 * lane;                                    \
        const float px[4] = {Ar.x, Ar.w, Br.z, Cr.y};                          \
        const float py[4] = {Ar.y, Br.x, Br.w, Cr.z};                          \
        const float pz[4] = {Ar.z, Br.y, Cr.x, Cr.w};                          \
        bool in[4];                                                            \
        unsigned long long m[4];                                               \
        _Pragma("unroll")                                                      \
        for (int k = 0; k < 4; ++k) {                                          \
            const float dx = px[k] - cx;                                       \
            const float dy = py[k] - cy;                                       \
            const float dz = pz[k] - cz;                                       \
            /* match numpy: plain f32 mul/add, left-to-right, NO fma */        \
            const float d2 = __fadd_rn(__fadd_rn(__fmul_rn(dx, dx),            \
                                                 __fmul_rn(dy, dy)),           \
                                       __fmul_rn(dz, dz));                     \
            in[k] = d2 < r2;                                                   \
            m[k] = __ballot(in[k]);                                            \
        }                                                                      \
        int pos = found                                                        \
                + (int)__popcll(m[0] & low) + (int)__popcll(m[1] & low)        \
                + (int)__popcll(m[2] & low) + (int)__popcll(m[3] & low);       \
        _Pragma("unroll")                                                      \
        for (int k = 0; k < 4; ++k) {                                          \
            if (in[k]) {                                                       \
                if (pos < NS) widx[pos] = n0 + k;                              \
                ++pos;                                                         \
            }                                                                  \
        }                                                                      \
        found += (int)(__popcll(m[0]) + __popcll(m[1])                         \
                     + __popcll(m[2]) + __popcll(m[3]));                       \
    }

    while (true) {
        QPROC(A0, B0, C0)                        // chunk it (set 0)
        if (found >= NS || it == NCHUNK - 1) break;
        {
            const int nit = (it + 2 < NCHUNK) ? it + 2 : it;
            const size_t nb = (size_t)nit * 192 + base;
            A0 = x4[nb]; B0 = x4[nb + 1]; C0 = x4[nb + 2];
        }
        ++it;
        QPROC(A1, B1, C1)                        // chunk it (set 1)
        if (found >= NS || it == NCHUNK - 1) break;
        {
            const int nit = (it + 2 < NCHUNK) ? it + 2 : it;
            const size_t nb = (size_t)nit * 192 + base;
            A1 = x4[nb]; B1 = x4[nb + 1]; C1 = x4[nb + 2];
        }
        ++it;
    }
#undef QPROC

    // ref fill semantics: pad with first found idx, 0 if none found
    int myidx = 0;
    if (found > 0) {
        const int first = widx[0];
        myidx = (lane < found) ? widx[lane] : first;
    }
    widx[lane] = myidx;   // full 64-slot idx table for the cooperative gather

    // ---- xyz channels (lane = sample slot; 256B-coalesced stores)
    const float* pp = xb + (size_t)myidx * 3;
    float* ob = out + (size_t)center * CH * NS;
    ob[0 * NS + lane] = pp[0] - cx;
    ob[1 * NS + lane] = pp[1] - cy;
    ob[2 * NS + lane] = pp[2] - cz;

    // ---- cooperative feature gather with dwordx4 stores (R12-identical)
    const float* ftb = ft + (size_t)b * NN * CC;
    float* tw = stile[wave];
    const int sub  = lane & 15;   // 16B chunk within a row
    const int rsub = lane >> 4;   // which of 4 rows this instr covers
    const int sq   = lane & 7;    // sample quad within half
    const int cc8  = lane >> 3;   // channel offset within group of 8

#pragma unroll
    for (int h = 0; h < 2; ++h) {
        int ridx[8];
#pragma unroll
        for (int i = 0; i < 8; ++i) ridx[i] = widx[32 * h + 4 * i + rsub];
        float4 v[8];
#pragma unroll
        for (int i = 0; i < 8; ++i)   // 8 dwordx4, contiguous 256B lane groups
            v[i] = *(const float4*)(ftb + (size_t)ridx[i] * CC + 4 * sub);
#pragma unroll
        for (int i = 0; i < 8; ++i) { // tile[sample][channel], <=2-way banks
            float* tr = tw + (4 * i + rsub) * ST + 4 * sub;
            tr[0] = v[i].x; tr[1] = v[i].y; tr[2] = v[i].z; tr[3] = v[i].w;
        }
#pragma unroll
        for (int t = 0; t < 8; ++t) { // 8 dwordx4 stores per half
            const int c = 8 * t + cc8;
            f32x4 u;
            u.x = tw[(4 * sq + 0) * ST + c];
            u.y = tw[(4 * sq + 1) * ST + c];
            u.z = tw[(4 * sq + 2) * ST + c];
            u.w = tw[(4 * sq + 3) * ST + c];
            float* o = ob + (size_t)(3 + c) * NS + 32 * h + 4 * sq;  // 16B aligned
            *(f32x4*)o = u;
        }
    }
}

// ---------- Fallback (ws too small): round-1 direct-gather kernel ----------
__global__ __launch_bounds__(256, 4) void pn2_group_kernel(
    const float* __restrict__ xyz, const float* __restrict__ new_xyz,
    const float* __restrict__ features, float* __restrict__ out)
{
    __shared__ int sidx[4][NS];
    const int lane = threadIdx.x & 63;
    const int wave = threadIdx.x >> 6;
    const int center = blockIdx.x * 4 + wave;
    const int b = center >> 11;
    const int j = center & (NP - 1);
    const float r2 = 0.04f;
    const float* q = new_xyz + ((size_t)b * NP + j) * 3;
    const float cx = q[0], cy = q[1], cz = q[2];
    int* widx = sidx[wave];
    int found = 0;
    for (int it = 0; it < NN / 64; ++it) {
        const int n = it * 64 + lane;
        const float* p = xyz + ((size_t)b * NN + n) * 3;
        const float dx = p[0] - cx, dy = p[1] - cy, dz = p[2] - cz;
        const float d2 = __fadd_rn(__fadd_rn(__fmul_rn(dx, dx), __fmul_rn(dy, dy)),
                                   __fmul_rn(dz, dz));
        const bool within = d2 < r2;
        const unsigned long long mask = __ballot(within);
        const int pos = found + (int)__popcll(mask & ((1ull << lane) - 1ull));
        if (within && pos < NS) widx[pos] = n;
        found += (int)__popcll(mask);
        if (found >= NS) break;
    }
    int myidx = 0;
    if (found > 0) {
        const int first = widx[0];
        myidx = (lane < found) ? widx[lane] : first;
    }
    const float* pp = xyz + ((size_t)b * NN + myidx) * 3;
    float* ob = out + (((size_t)b * NP + j) * (size_t)CH) * NS + lane;
    ob[0 * NS] = pp[0] - cx;
    ob[1 * NS] = pp[1] - cy;
    ob[2 * NS] = pp[2] - cz;
    const float* fb = features + (size_t)b * CC * NN + myidx;
#pragma unroll 8
    for (int c = 0; c < CC; ++c) ob[(size_t)(3 + c) * NS] = fb[(size_t)c * NN];
}

extern "C" void kernel_launch(void* const* d_in, const int* in_sizes, int n_in,
                              void* d_out, int out_size, void* d_ws, size_t ws_size,
                              hipStream_t stream) {
    const float* xyz      = (const float*)d_in[0];
    const float* new_xyz  = (const float*)d_in[1];
    const float* features = (const float*)d_in[2];
    float* out = (float*)d_out;

    const size_t ft_bytes    = (size_t)BB * NN * CC * sizeof(float); // 16.8 MB
    const size_t remap_bytes = (size_t)BB * NP * sizeof(int);        // 32 KB

    if (ws_size >= ft_bytes + remap_bytes) {
        float* ft  = (float*)d_ws;
        int* remap = (int*)((char*)d_ws + ft_bytes);
        pn2_prep_kernel<<<BB * 256 + BB, 256, 0, stream>>>(features, new_xyz,
                                                           ft, remap);
        pn2_qg_kernel<<<BB * NP / 4, 256, 0, stream>>>(xyz, new_xyz, ft,
                                                       remap, out);
    } else {
        pn2_group_kernel<<<BB * NP / 4, 256, 0, stream>>>(xyz, new_xyz, features, out);
    }
}

// Round 14
// 43.990 us; speedup vs baseline: 1.6764x; 1.6764x over previous
//
#include <hip/hip_runtime.h>

// PointNet++ grouping: ball query (radius 0.2, nsample 64) + gather + concat.
// Shapes fixed by setup_inputs(): B=4, N=16384, npoint=2048, C=64.
// out[b][j][c][s]: c in [0,3) = xyz[idx]-new_xyz, c in [3,67) = features[c-3][idx].
//
// Structure (round 14 = exact restore of round 12, the session best: 44.06us):
//   Kernel 1: transpose features (B,C,N) -> ft (B,N,C) in ws, XCD-pinned so
//     batch b's ft write-allocates into XCD pair b's L2.
//   Kernel 2: fused query + cooperative gather, 4 waves/block, regular
//     (non-NT) dwordx4 stores. Per wave: ball-query scan (4 pts/lane via
//     3x float4, prefetch-1), then 16-lane-per-row cooperative gather of
//     contiguous 256B ft rows through a [32][65] LDS transpose tile, then
//     19 dwordx4 output stores.
//   Session ledger (all single-kernel dur_us): fused beats split (R8 +8.5),
//   barrier-free beats lockstep (R9 +13), 4-wave beats 1-wave (R10 +21),
//   LDS-capped 4 blk/CU beats VGPR-capped 8 blk/CU (R11 +13), identity
//   schedule beats LPT remap (R13 +30, write-locality loss), regular
//   stores beat NT stores (R12 -2). Remaining ~15us over the 22us write
//   floor is latency-bound query/gather work; five overlap mechanisms all
//   regressed, so this is the structure's practical floor.

#define BB 4
#define NN 16384
#define NP 2048
#define CC 64
#define NS 64
#define CH (3 + CC)
#define NCHUNK (NN / 256)   // 64 chunks of 256 points
#define ST 65               // LDS tile row stride (floats)

typedef float f32x4 __attribute__((ext_vector_type(4)));

// ---------- Kernel 1: features (B,C,N) -> ft (B,N,C), XCD-pinned ----------
__global__ __launch_bounds__(256) void pn2_transpose_kernel(
    const float* __restrict__ f, float* __restrict__ ft)
{
    __shared__ float tile[CC][65];           // +1 pad: conflict-free both ways
    const int g = blockIdx.x;                // 1024 blocks
    const int xcd = g & 7;
    const int b = xcd >> 1;                  // batch pinned to XCD pair
    const int tidx = ((xcd & 1) << 7) + (g >> 3);   // 0..255
    const int n0 = tidx << 6;
    const int col = threadIdx.x & 63;
    const int r4  = threadIdx.x >> 6;        // 0..3
    const float* src = f + (size_t)b * CC * NN;
#pragma unroll
    for (int i = 0; i < 16; ++i) {
        const int c = r4 + i * 4;
        tile[c][col] = __builtin_nontemporal_load(&src[(size_t)c * NN + n0 + col]);
    }
    __syncthreads();
    float* dst = ft + ((size_t)b * NN + n0) * CC;
#pragma unroll
    for (int i = 0; i < 16; ++i) {
        const int n = r4 + i * 4;
        dst[(size_t)n * CC + col] = tile[col][n];        // coalesced along c
    }
}

// ---------- Kernel 2: fused ball query + cooperative gather ----------
__global__ __launch_bounds__(256, 4) void pn2_qg_kernel(
    const float* __restrict__ xyz,       // (B, N, 3)
    const float* __restrict__ new_xyz,   // (B, NP, 3)
    const float* __restrict__ ft,        // ws: (B, N, C)
    float* __restrict__ out)             // (B, NP, CH, NS)
{
    __shared__ int sidx[4][NS];
    __shared__ __align__(16) float stile[4][32 * ST];   // 33.3KB: half/wave

    const int lane = threadIdx.x & 63;
    const int wave = threadIdx.x >> 6;

    // XCD batch pinning (matches transpose): bijective over 2048 blocks.
    const int g = blockIdx.x;
    const int xcd = g & 7;
    const int cg = ((xcd >> 1) << 9) + ((xcd & 1) << 8) + (g >> 3);
    const int center = cg * 4 + wave;           // 0 .. B*NP-1
    const int b = center >> 11;
    const int j = center & (NP - 1);

    const float r2 = 0.04f;                     // f32(0.2*0.2)
    const float* q = new_xyz + ((size_t)b * NP + j) * 3;
    const float cx = q[0], cy = q[1], cz = q[2];

    const float* xb = xyz + (size_t)b * NN * 3;
    const float4* x4 = (const float4*)xb;
    int* widx = sidx[wave];

    // ---- query: 4 points/lane (48B = 3x float4), prefetch one chunk ahead
    const int base = 3 * lane;
    const unsigned long long low = (1ull << lane) - 1ull;
    int found = 0;
    int it = 0;
    float4 A = x4[base], Bv = x4[base + 1], Cv = x4[base + 2];

    while (true) {
        const int nit = (it + 1 < NCHUNK) ? it + 1 : it;
        const size_t nb = (size_t)nit * 192 + base;
        float4 nA = x4[nb], nB = x4[nb + 1], nC = x4[nb + 2];

        const int n0 = it * 256 + 4 * lane;
        const float px[4] = {A.x, A.w, Bv.z, Cv.y};
        const float py[4] = {A.y, Bv.x, Bv.w, Cv.z};
        const float pz[4] = {A.z, Bv.y, Cv.x, Cv.w};
        bool in[4];
        unsigned long long m[4];
#pragma unroll
        for (int k = 0; k < 4; ++k) {
            const float dx = px[k] - cx;
            const float dy = py[k] - cy;
            const float dz = pz[k] - cz;
            // match numpy: plain f32 mul/add, left-to-right, NO fma contraction
            const float d2 = __fadd_rn(__fadd_rn(__fmul_rn(dx, dx), __fmul_rn(dy, dy)),
                                       __fmul_rn(dz, dz));
            in[k] = d2 < r2;
            m[k] = __ballot(in[k]);
        }
        int pos = found
                + (int)__popcll(m[0] & low) + (int)__popcll(m[1] & low)
                + (int)__popcll(m[2] & low) + (int)__popcll(m[3] & low);
#pragma unroll
        for (int k = 0; k < 4; ++k) {
            if (in[k]) {
                if (pos < NS) widx[pos] = n0 + k;
                ++pos;
            }
        }
        found += (int)(__popcll(m[0]) + __popcll(m[1])
                     + __popcll(m[2]) + __popcll(m[3]));     // wave-uniform
        if (found >= NS || it == NCHUNK - 1) break;          // uniform branch
        A = nA; Bv = nB; Cv = nC; ++it;
    }

    // ref fill semantics: pad with first found idx, 0 if none found
    int myidx = 0;
    if (found > 0) {
        const int first = widx[0];
        myidx = (lane < found) ? widx[lane] : first;
    }
    widx[lane] = myidx;   // full 64-slot idx table for the cooperative gather

    // ---- xyz channels (lane = sample slot; 256B-coalesced stores)
    const float* pp = xb + (size_t)myidx * 3;
    float* ob = out + (size_t)center * CH * NS;
    ob[0 * NS + lane] = pp[0] - cx;
    ob[1 * NS + lane] = pp[1] - cy;
    ob[2 * NS + lane] = pp[2] - cz;

    // ---- cooperative feature gather with dwordx4 stores
    // load side:  lane = (rsub, sub): 16 lanes x 16B per 256B row; one
    //             dwordx4 instr covers 4 rows (16 line-lookups/instr).
    // store side: lane = (cc8, sq): f32x4 = samples 4sq..4sq+3 of channel
    //             8t+cc8; one dwordx4 instr covers 8 channel-row 128B segs.
    const float* ftb = ft + (size_t)b * NN * CC;
    float* tw = stile[wave];
    const int sub  = lane & 15;   // 16B chunk within a row
    const int rsub = lane >> 4;   // which of 4 rows this instr covers
    const int sq   = lane & 7;    // sample quad within half
    const int cc8  = lane >> 3;   // channel offset within group of 8

#pragma unroll
    for (int h = 0; h < 2; ++h) {
        int ridx[8];
#pragma unroll
        for (int i = 0; i < 8; ++i) ridx[i] = widx[32 * h + 4 * i + rsub];
        float4 v[8];
#pragma unroll
        for (int i = 0; i < 8; ++i)   // 8 dwordx4, contiguous 256B lane groups
            v[i] = *(const float4*)(ftb + (size_t)ridx[i] * CC + 4 * sub);
#pragma unroll
        for (int i = 0; i < 8; ++i) { // tile[sample][channel], <=2-way banks
            float* tr = tw + (4 * i + rsub) * ST + 4 * sub;
            tr[0] = v[i].x; tr[1] = v[i].y; tr[2] = v[i].z; tr[3] = v[i].w;
        }
#pragma unroll
        for (int t = 0; t < 8; ++t) { // 8 dwordx4 stores per half
            const int c = 8 * t + cc8;
            f32x4 u;
            u.x = tw[(4 * sq + 0) * ST + c];
            u.y = tw[(4 * sq + 1) * ST + c];
            u.z = tw[(4 * sq + 2) * ST + c];
            u.w = tw[(4 * sq + 3) * ST + c];
            float* o = ob + (size_t)(3 + c) * NS + 32 * h + 4 * sq;  // 16B aligned
            *(f32x4*)o = u;
        }
    }
}

// ---------- Fallback (ws too small): round-1 direct-gather kernel ----------
__global__ __launch_bounds__(256, 4) void pn2_group_kernel(
    const float* __restrict__ xyz, const float* __restrict__ new_xyz,
    const float* __restrict__ features, float* __restrict__ out)
{
    __shared__ int sidx[4][NS];
    const int lane = threadIdx.x & 63;
    const int wave = threadIdx.x >> 6;
    const int center = blockIdx.x * 4 + wave;
    const int b = center >> 11;
    const int j = center & (NP - 1);
    const float r2 = 0.04f;
    const float* q = new_xyz + ((size_t)b * NP + j) * 3;
    const float cx = q[0], cy = q[1], cz = q[2];
    int* widx = sidx[wave];
    int found = 0;
    for (int it = 0; it < NN / 64; ++it) {
        const int n = it * 64 + lane;
        const float* p = xyz + ((size_t)b * NN + n) * 3;
        const float dx = p[0] - cx, dy = p[1] - cy, dz = p[2] - cz;
        const float d2 = __fadd_rn(__fadd_rn(__fmul_rn(dx, dx), __fmul_rn(dy, dy)),
                                   __fmul_rn(dz, dz));
        const bool within = d2 < r2;
        const unsigned long long mask = __ballot(within);
        const int pos = found + (int)__popcll(mask & ((1ull << lane) - 1ull));
        if (within && pos < NS) widx[pos] = n;
        found += (int)__popcll(mask);
        if (found >= NS) break;
    }
    int myidx = 0;
    if (found > 0) {
        const int first = widx[0];
        myidx = (lane < found) ? widx[lane] : first;
    }
    const float* pp = xyz + ((size_t)b * NN + myidx) * 3;
    float* ob = out + (((size_t)b * NP + j) * (size_t)CH) * NS + lane;
    ob[0 * NS] = pp[0] - cx;
    ob[1 * NS] = pp[1] - cy;
    ob[2 * NS] = pp[2] - cz;
    const float* fb = features + (size_t)b * CC * NN + myidx;
#pragma unroll 8
    for (int c = 0; c < CC; ++c) ob[(size_t)(3 + c) * NS] = fb[(size_t)c * NN];
}

extern "C" void kernel_launch(void* const* d_in, const int* in_sizes, int n_in,
                              void* d_out, int out_size, void* d_ws, size_t ws_size,
                              hipStream_t stream) {
    const float* xyz      = (const float*)d_in[0];
    const float* new_xyz  = (const float*)d_in[1];
    const float* features = (const float*)d_in[2];
    float* out = (float*)d_out;

    const size_t ft_bytes = (size_t)BB * NN * CC * sizeof(float);   // 16.8 MB

    if (ws_size >= ft_bytes) {
        float* ft = (float*)d_ws;
        pn2_transpose_kernel<<<BB * 256, 256, 0, stream>>>(features, ft);
        pn2_qg_kernel<<<BB * NP / 4, 256, 0, stream>>>(xyz, new_xyz, ft, out);
    } else {
        pn2_group_kernel<<<BB * NP / 4, 256, 0, stream>>>(xyz, new_xyz, features, out);
    }
}